// Round 5
// baseline (104.766 us; speedup 1.0000x reference)
//
#include <hip/hip_runtime.h>

// BoxFilter: out = 9x9 box SUM of x with zero padding == reference
// diff_y(diff_x(cumsum_H(x),4).cumsum_W,4). fp32 in/out, 48 x 1024x1024.
//
// R5 = R4 + two changes targeting the phase-1 vmcnt stall:
//  - dp (drop rows) prefetched ONE GROUP EARLY like nx: every load consumed
//    in phase 1 has been in flight for a full group -> ~zero vmcnt wait.
//    (R4 loaded dp in the same phase it was consumed -> ~250cy L2 stall
//    before the 2nd LDS publish, serializing every group.)
//  - vlds double-buffered (2 x 4 x 1032 f32 = 33KB) -> second barrier
//    deleted; one s_barrier per 4-row group. A wave can't get a full group
//    ahead (next barrier gates it), so buf[p^1] writes never race buf[p] reads.

#define RR 4
#define HH 1024
#define WW 1024
#define BLOCK 256
#define TILE 32
#define GROUP 4
#define NG (TILE / GROUP)
#define LDSW (WW + 2 * RR) // 1032

typedef float f32x4 __attribute__((ext_vector_type(4)));

__device__ __forceinline__ float4 zero4() {
    float4 z; z.x = 0.f; z.y = 0.f; z.z = 0.f; z.w = 0.f; return z;
}
__device__ __forceinline__ void add4(float4& a, const float4 b) {
    a.x += b.x; a.y += b.y; a.z += b.z; a.w += b.w;
}
__device__ __forceinline__ void accdiff(float4& a, const float4 b, const float4 c) {
    a.x += b.x - c.x; a.y += b.y - c.y; a.z += b.z - c.z; a.w += b.w - c.w;
}
__device__ __forceinline__ void nt_store4(float* p, const float4 o) {
    f32x4 t; t.x = o.x; t.y = o.y; t.z = o.z; t.w = o.w;
    __builtin_nontemporal_store(t, (f32x4*)p);
}

__global__ __launch_bounds__(BLOCK) void box9_kernel(const float* __restrict__ x,
                                                     float* __restrict__ out) {
    const int tid = threadIdx.x;
    const int img = blockIdx.y;
    const int r0  = blockIdx.x * TILE;
    const size_t ioff = (size_t)img * HH * WW;
    const float* __restrict__ xi = x + ioff;
    float* __restrict__ oi       = out + ioff;
    const int c = 4 * tid;

    __shared__ float vlds[2][GROUP][LDSW];

    // constant zero column halos in BOTH buffers; written once before the
    // first barrier, never overwritten.
    if (tid < GROUP) {
#pragma unroll
        for (int p = 0; p < 2; ++p) {
            vlds[p][tid][0] = 0.f; vlds[p][tid][1] = 0.f;
            vlds[p][tid][2] = 0.f; vlds[p][tid][3] = 0.f;
            vlds[p][tid][LDSW - 4] = 0.f; vlds[p][tid][LDSW - 3] = 0.f;
            vlds[p][tid][LDSW - 2] = 0.f; vlds[p][tid][LDSW - 1] = 0.f;
        }
    }

    // v = vertical 9-sum at row r0 (rows r0-4..r0+4; top rows masked to zero)
    float4 v = zero4();
#pragma unroll
    for (int k = -RR; k <= RR; ++k) {
        const int r = r0 + k;
        if (r >= 0) add4(v, *(const float4*)(xi + (size_t)r * WW + c));
    }
    // group 0 prefetch: add rows r0+5..r0+8 (always valid, r0 <= 992) and
    // drop rows r0-4..r0-1 (masked at the top edge)
    float4 nx[GROUP], dp[GROUP];
#pragma unroll
    for (int k = 0; k < GROUP; ++k)
        nx[k] = *(const float4*)(xi + (size_t)(r0 + RR + 1 + k) * WW + c);
#pragma unroll
    for (int k = 0; k < GROUP; ++k) {
        const int rd = r0 - RR + k;
        dp[k] = (rd >= 0) ? *(const float4*)(xi + (size_t)rd * WW + c) : zero4();
    }

    int p = 0;
    for (int g = 0; g < NG; ++g, p ^= 1) {
        const int b = r0 + g * GROUP;

        // ---- phase 1: issue group g+1's loads, publish v-rows, advance v.
        // All loads CONSUMED here (nx, dp) were issued one group ago.
        float4 nnx[GROUP], dpn[GROUP];
#pragma unroll
        for (int k = 0; k < GROUP; ++k) { // add rows b+9..b+12 (HBM stream)
            const int rn = b + 2 * RR + 1 + k;
            nnx[k] = (rn < HH) ? *(const float4*)(xi + (size_t)rn * WW + c) : zero4();
        }
#pragma unroll
        for (int k = 0; k < GROUP; ++k) { // drop rows b..b+3 (L1/L2 hit)
            dpn[k] = *(const float4*)(xi + (size_t)(b + k) * WW + c);
        }
#pragma unroll
        for (int k = 0; k < GROUP; ++k) {
            *(float4*)(&vlds[p][k][4 + c]) = v;
            accdiff(v, nx[k], dp[k]);
        }
        asm volatile("s_waitcnt lgkmcnt(0)" ::: "memory"); // LDS visible; vmcnt NOT drained
        __builtin_amdgcn_s_barrier();

        // ---- phase 2: horizontal 9-tap sliding sum from LDS, NT store.
        // No trailing barrier: next group writes the OTHER buffer, and the
        // next barrier stops any wave from lapping a full group.
#pragma unroll
        for (int k = 0; k < GROUP; ++k) {
            const float4 a0 = *(const float4*)(&vlds[p][k][c]);
            const float4 a1 = *(const float4*)(&vlds[p][k][c + 4]);
            const float4 a2 = *(const float4*)(&vlds[p][k][c + 8]);
            float4 o;
            o.x = a0.x + a0.y + a0.z + a0.w + a1.x + a1.y + a1.z + a1.w + a2.x;
            o.y = o.x - a0.x + a2.y;
            o.z = o.y - a0.y + a2.z;
            o.w = o.z - a0.z + a2.w;
            nt_store4(oi + (size_t)(b + k) * WW + c, o);
        }

#pragma unroll
        for (int k = 0; k < GROUP; ++k) { nx[k] = nnx[k]; dp[k] = dpn[k]; }
    }
}

extern "C" void kernel_launch(void* const* d_in, const int* in_sizes, int n_in,
                              void* d_out, int out_size, void* d_ws, size_t ws_size,
                              hipStream_t stream) {
    const float* x = (const float*)d_in[0];
    float* out     = (float*)d_out;
    const int nimg = in_sizes[0] / (HH * WW); // 48
    dim3 grid(HH / TILE, nimg, 1);            // (32, 48) = 1536 blocks
    box9_kernel<<<grid, BLOCK, 0, stream>>>(x, out);
}

// Round 6
// 69.753 us; speedup vs baseline: 1.5020x; 1.5020x over previous
//
#include <hip/hip_runtime.h>

// BoxFilter: out = 9x9 box SUM of x with zero padding == reference
// diff_y(diff_x(cumsum_H(x),4).cumsum_W,4). fp32 in/out, 48 x 1024x1024.
//
// R6 = R5 + register shift-history: each thread keeps the last 9 x-rows
// (its 4 columns) in registers, so the vertical-window advance needs NO
// drop-row reload (R1-R5 re-read drop rows from L1/L2). Read instructions
// per 4-row group: 8 -> 4; every input element is loaded exactly once per
// block. Tests the VMEM-instruction-rate hypothesis for the 4.3 TB/s
// convergence of R1/R2/R4/R5.
//  - TILE=64 -> 768 blocks (3/CU), vertical halo 73/64 = 1.14x
//  - one lgkmcnt(0)+s_barrier per 4-row group, vlds double-buffered
//    (wave's phase-2 ds_reads drain at its NEXT group's lgkmcnt(0),
//    before any same-buffer overwrite can pass that barrier)
//  - NT stores; output never re-read

#define RR 4
#define HH 1024
#define WW 1024
#define BLOCK 256
#define TILE 64
#define GROUP 4
#define NG (TILE / GROUP)
#define LDSW (WW + 2 * RR) // 1032

typedef float f32x4 __attribute__((ext_vector_type(4)));

__device__ __forceinline__ float4 zero4() {
    float4 z; z.x = 0.f; z.y = 0.f; z.z = 0.f; z.w = 0.f; return z;
}
__device__ __forceinline__ void add4(float4& a, const float4 b) {
    a.x += b.x; a.y += b.y; a.z += b.z; a.w += b.w;
}
__device__ __forceinline__ void accdiff(float4& a, const float4 b, const float4 c) {
    a.x += b.x - c.x; a.y += b.y - c.y; a.z += b.z - c.z; a.w += b.w - c.w;
}
__device__ __forceinline__ void nt_store4(float* p, const float4 o) {
    f32x4 t; t.x = o.x; t.y = o.y; t.z = o.z; t.w = o.w;
    __builtin_nontemporal_store(t, (f32x4*)p);
}

__global__ __launch_bounds__(BLOCK, 4) void box9_kernel(const float* __restrict__ x,
                                                        float* __restrict__ out) {
    const int tid = threadIdx.x;
    const int img = blockIdx.y;
    const int r0  = blockIdx.x * TILE;
    const size_t ioff = (size_t)img * HH * WW;
    const float* __restrict__ xi = x + ioff;
    float* __restrict__ oi       = out + ioff;
    const int c = 4 * tid;

    __shared__ float vlds[2][GROUP][LDSW];

    // constant zero column halos in both buffers (cols -4..-1, 1024..1027);
    // written once; drained by this wave's lgkmcnt(0) before the first barrier.
    if (tid < GROUP) {
#pragma unroll
        for (int p = 0; p < 2; ++p) {
            vlds[p][tid][0] = 0.f; vlds[p][tid][1] = 0.f;
            vlds[p][tid][2] = 0.f; vlds[p][tid][3] = 0.f;
            vlds[p][tid][LDSW - 4] = 0.f; vlds[p][tid][LDSW - 3] = 0.f;
            vlds[p][tid][LDSW - 2] = 0.f; vlds[p][tid][LDSW - 1] = 0.f;
        }
    }

    // history h[j] = x row (r0-4+j), j=0..8 (zero above the image);
    // v = vertical 9-sum at row r0; n = add rows r0+5..r0+8 (always valid).
    float4 h[9], n[GROUP], m[GROUP], v = zero4();
#pragma unroll
    for (int j = 0; j < 9; ++j) {
        const int r = r0 - RR + j;
        h[j] = (r >= 0) ? *(const float4*)(xi + (size_t)r * WW + c) : zero4();
        add4(v, h[j]);
    }
#pragma unroll
    for (int k = 0; k < GROUP; ++k)
        n[k] = *(const float4*)(xi + (size_t)(r0 + RR + 1 + k) * WW + c);

    int p = 0;
    for (int g = 0; g < NG; ++g, p ^= 1) {
        const int b = r0 + g * GROUP;

        // ---- phase 1: issue next group's add rows, publish v-rows, advance.
        // h[0..3] are exactly drop rows b-4..b-1; no memory dependency.
#pragma unroll
        for (int k = 0; k < GROUP; ++k) { // rows b+9..b+12 (sole HBM read stream)
            const int rn = b + 2 * RR + 1 + k;
            m[k] = (rn < HH) ? *(const float4*)(xi + (size_t)rn * WW + c) : zero4();
        }
#pragma unroll
        for (int k = 0; k < GROUP; ++k) {
            *(float4*)(&vlds[p][k][4 + c]) = v;
            accdiff(v, n[k], h[k]);
        }
        asm volatile("s_waitcnt lgkmcnt(0)" ::: "memory"); // LDS visible; vmcnt NOT drained
        __builtin_amdgcn_s_barrier();

        // ---- phase 2: horizontal 9-tap sliding sum from LDS, NT store
#pragma unroll
        for (int k = 0; k < GROUP; ++k) {
            const float4 a0 = *(const float4*)(&vlds[p][k][c]);
            const float4 a1 = *(const float4*)(&vlds[p][k][c + 4]);
            const float4 a2 = *(const float4*)(&vlds[p][k][c + 8]);
            float4 o;
            o.x = a0.x + a0.y + a0.z + a0.w + a1.x + a1.y + a1.z + a1.w + a2.x;
            o.y = o.x - a0.x + a2.y;
            o.z = o.y - a0.y + a2.z;
            o.w = o.z - a0.z + a2.w;
            nt_store4(oi + (size_t)(b + k) * WW + c, o);
        }

        // ---- shift history by 4 rows (static indices -> stays in VGPRs)
#pragma unroll
        for (int j = 0; j < 5; ++j) h[j] = h[j + 4];
#pragma unroll
        for (int k = 0; k < GROUP; ++k) { h[5 + k] = n[k]; n[k] = m[k]; }
    }
}

extern "C" void kernel_launch(void* const* d_in, const int* in_sizes, int n_in,
                              void* d_out, int out_size, void* d_ws, size_t ws_size,
                              hipStream_t stream) {
    const float* x = (const float*)d_in[0];
    float* out     = (float*)d_out;
    const int nimg = in_sizes[0] / (HH * WW); // 48
    dim3 grid(HH / TILE, nimg, 1);            // (16, 48) = 768 blocks
    box9_kernel<<<grid, BLOCK, 0, stream>>>(x, out);
}